// Round 5
// baseline (4905.137 us; speedup 1.0000x reference)
//
#include <hip/hip_runtime.h>

#define BB 16
#define LL 512
#define DD 128

// padded word index for exchanged vectors: +4 words per 16-word chunk ->
// the 8 j-lanes' float4 reads cover all 8 bank-groups (conflict-free)
#define PADW(c) ((c) + (((c) >> 4) << 2))

// 8-lane all-reduce sum (octet = DPP half-row), pure VALU:
// quad xor1, quad xor2, then half-row mirror pairs the two quads.
__device__ __forceinline__ float red8(float v) {
    v += __int_as_float(__builtin_amdgcn_update_dpp(
            0, __float_as_int(v), 0xB1, 0xF, 0xF, true));
    v += __int_as_float(__builtin_amdgcn_update_dpp(
            0, __float_as_int(v), 0x4E, 0xF, 0xF, true));
    v += __int_as_float(__builtin_amdgcn_update_dpp(
            0, __float_as_int(v), 0x141, 0xF, 0xF, true));
    return v;
}

// ---------------- transpose Wq, Wk, Wout (once per call, tiny) ----------------
__global__ void transpose3_kernel(const float* __restrict__ Wq,
                                  const float* __restrict__ Wk,
                                  const float* __restrict__ Wout,
                                  float* __restrict__ WqT,
                                  float* __restrict__ WkT,
                                  float* __restrict__ WoutT) {
    const float* src; float* dst;
    if (blockIdx.x == 0)      { src = Wq;   dst = WqT;   }
    else if (blockIdx.x == 1) { src = Wk;   dst = WkT;   }
    else                      { src = Wout; dst = WoutT; }
    for (int idx = threadIdx.x; idx < DD * DD; idx += blockDim.x) {
        int r = idx >> 7, c = idx & 127;
        dst[c * DD + r] = src[idx];
    }
}

// ---------------- prologue: q/k projections, k-normalize, P0 rotation, poly ----
__global__ __launch_bounds__(128) void prologue_kernel(
        const float* __restrict__ x, const float* __restrict__ WqT,
        const float* __restrict__ WkT, const float* __restrict__ P0,
        const float* __restrict__ log_gain, const float* __restrict__ coeffs,
        float* __restrict__ kphi, float* __restrict__ qphi) {
    const int row0 = blockIdx.x * 4;
    const int e = threadIdx.x;
    __shared__ float xs[4][DD];
    __shared__ float qrow[4][DD];
    __shared__ float wred[4][2];

    #pragma unroll
    for (int rr = 0; rr < 4; ++rr)
        xs[rr][e] = x[(size_t)(row0 + rr) * DD + e];
    __syncthreads();

    float aq[4] = {0,0,0,0}, ak[4] = {0,0,0,0};
    #pragma unroll 4
    for (int d = 0; d < DD; ++d) {
        float wq = WqT[d * DD + e];
        float wk = WkT[d * DD + e];
        #pragma unroll
        for (int rr = 0; rr < 4; ++rr) {
            float xv = xs[rr][d];
            aq[rr] = fmaf(xv, wq, aq[rr]);
            ak[rr] = fmaf(xv, wk, ak[rr]);
        }
    }
    const int lane = threadIdx.x & 63, wv = threadIdx.x >> 6;
    #pragma unroll
    for (int rr = 0; rr < 4; ++rr) {
        float s = ak[rr] * ak[rr];
        #pragma unroll
        for (int m = 1; m <= 32; m <<= 1) s += __shfl_xor(s, m);
        if (lane == 0) wred[rr][wv] = s;
    }
    __syncthreads();
    const float c0 = coeffs[0], c1v = coeffs[1];
    #pragma unroll
    for (int rr = 0; rr < 4; ++rr) {
        float s = wred[rr][0] + wred[rr][1];
        float kn = ak[rr] / fmaxf(sqrtf(s), 1e-12f);
        kphi[(size_t)(row0 + rr) * DD + e] = c0 * kn + c1v * kn * kn;
        qrow[rr][e] = aq[rr];
    }
    __syncthreads();
    float acc[4] = {0,0,0,0};
    #pragma unroll 4
    for (int d = 0; d < DD; ++d) {
        float pv = P0[d * DD + e];
        #pragma unroll
        for (int rr = 0; rr < 4; ++rr) acc[rr] = fmaf(qrow[rr][d], pv, acc[rr]);
    }
    const float g = expf(log_gain[e]);
    #pragma unroll
    for (int rr = 0; rr < 4; ++rr) {
        float qa = tanhf(g * acc[rr]);
        qphi[(size_t)(row0 + rr) * DD + e] = c0 * qa + c1v * qa * qa;
    }
}

// ---------------- main sequential scan: one block per batch --------------------
// 1024 threads = 16 waves = 4 waves/SIMD (vs 2 in the 512-thread version) for
// latency hiding. Thread (r = tid>>3, j = tid&7): row r x cols [16j,16j+16) of
// S, A, M, plus ST[r][c] = S[c][r] (transpose slice, same col chunk). All
// reductions are 8-lane DPP butterflies. Exchanged vectors in bank-padded LDS.
// A = S S^T S via exact rank-3 recurrence; ||S||_F^2 via scalar recurrence.
// Phase 6 runs in two 8-col halves and re-reads k from LDS to stay under the
// 128-VGPR cap (4 waves/SIMD).
__global__ __launch_bounds__(1024, 4) void scan_kernel(
        const float* __restrict__ kphi, const float* __restrict__ qphi,
        const float* __restrict__ x, const float* __restrict__ M0,
        const float* __restrict__ S0, float* __restrict__ ys) {
    const int b   = blockIdx.x;
    const int tid = threadIdx.x;
    const int j   = tid & 7;
    const int r   = tid >> 3;

    __shared__ __align__(16) float kq[2][320];   // k at PADW(c), q at 160+PADW(c)
    __shared__ __align__(16) float xr[2][160];
    __shared__ __align__(16) float us[160], ps[160], wsv[160], hs[160];
    __shared__ float red[DD];
    __shared__ float n2sh[2];

    float S[16], ST[16], A[16], M[16];
    {
        const float4* S04 = (const float4*)S0;
        const float4* M04 = (const float4*)M0;
        #pragma unroll
        for (int m = 0; m < 4; ++m) {
            int f4 = r * 32 + 4 * j + m;
            float4 s4 = S04[f4], m4 = M04[f4];
            int i = 4 * m;
            S[i+0] = s4.x; S[i+1] = s4.y; S[i+2] = s4.z; S[i+3] = s4.w;
            M[i+0] = m4.x; M[i+1] = m4.y; M[i+2] = m4.z; M[i+3] = m4.w;
        }
        #pragma unroll
        for (int cl = 0; cl < 16; ++cl)
            ST[cl] = S0[(size_t)(16 * j + cl) * DD + r];
        #pragma unroll
        for (int i = 0; i < 16; ++i) A[i] = 0.f;     // exact when S0 == 0
    }

    // ||S0||^2 block reduction + stage t=0 vectors
    float sp = 0.f;
    #pragma unroll
    for (int i = 0; i < 16; ++i) sp = fmaf(S[i], S[i], sp);
    sp = red8(sp);
    if (j == 0) red[r] = sp;

    const size_t base = (size_t)b * LL * DD;
    if (tid < 32) {
        ((float4*)kq[0])[tid + (tid >> 2)] = *(const float4*)(kphi + base + 4 * tid);
    } else if (tid < 64) {
        int c4 = tid - 32;
        ((float4*)kq[0])[40 + c4 + (c4 >> 2)] = *(const float4*)(qphi + base + 4 * c4);
    } else if (tid < 96) {
        int c4 = tid - 64;
        ((float4*)xr[0])[c4 + (c4 >> 2)] = *(const float4*)(x + base + 4 * c4);
    }
    __syncthreads();
    if (tid < 128) {
        float s = red[tid];
        #pragma unroll
        for (int m = 1; m <= 32; m <<= 1) s += __shfl_xor(s, m);
        if ((tid & 63) == 0) n2sh[tid >> 6] = s;
    }
    __syncthreads();
    float n2 = n2sh[0] + n2sh[1];

    const float a = 0.9f, a2v = 0.81f, a3v = 0.729f;

    for (int t = 0; t < LL; ++t) {
        const int buf = t & 1, nbuf = buf ^ 1;
        const float* kqb = kq[buf];

        // ---- phase 2 (row side): pred = M k, p = S v, cv = v.v ----
        float pr = 0.f, pp = 0.f, cvp = 0.f;
        {
            const float4* k4 = (const float4*)kqb;
            #pragma unroll
            for (int m = 0; m < 4; ++m) {
                float4 v4 = k4[5 * j + m];
                float vv[4] = {v4.x, v4.y, v4.z, v4.w};
                #pragma unroll
                for (int l = 0; l < 4; ++l) {
                    int i = 4 * m + l;
                    pr  = fmaf(M[i], vv[l], pr);
                    pp  = fmaf(S[i], vv[l], pp);
                    cvp = fmaf(vv[l], vv[l], cvp);
                }
            }
        }
        pr = red8(pr); pp = red8(pp);
        const float cv  = red8(cvp);
        const float x_r = xr[buf][PADW(r)];
        const float u_r = pr - x_r;     // err
        const float p_r = pp;
        if (j == 0) { us[PADW(r)] = u_r; ps[PADW(r)] = p_r; }
        __syncthreads();                               // barrier 1

        // staging loads for t+1 (in flight across phase 4)
        const int tn = (t + 1 < LL) ? (t + 1) : (LL - 1);
        const size_t nb = base + (size_t)tn * DD;
        float4 pre;
        if (tid < 32)       pre = *(const float4*)(kphi + nb + 4 * tid);
        else if (tid < 64)  pre = *(const float4*)(qphi + nb + 4 * (tid - 32));
        else if (tid < 96)  pre = *(const float4*)(x + nb + 4 * (tid - 64));

        // ---- phase 4 (col side): w = S^T u, h = S^T p, dots; ST update ----
        const float v_r = kqb[PADW(r)];
        float wp = 0.f, hp = 0.f, cuup = 0.f, cupp = 0.f;
        {
            const float4* u4 = (const float4*)us;
            const float4* p4 = (const float4*)ps;
            #pragma unroll
            for (int m = 0; m < 4; ++m) {
                float4 a4 = u4[5 * j + m], b4 = p4[5 * j + m];
                float uu[4] = {a4.x, a4.y, a4.z, a4.w};
                float pa[4] = {b4.x, b4.y, b4.z, b4.w};
                #pragma unroll
                for (int l = 0; l < 4; ++l) {
                    int i = 4 * m + l;
                    float st = ST[i];
                    wp   = fmaf(st, uu[l], wp);
                    hp   = fmaf(st, pa[l], hp);
                    cuup = fmaf(uu[l], uu[l], cuup);
                    cupp = fmaf(uu[l], pa[l], cupp);
                    ST[i] = fmaf(a, st, v_r * uu[l]);   // old st used above only
                }
            }
        }
        const float w_r = red8(wp);
        const float h_r = red8(hp);
        const float cu  = red8(cuup);
        const float cup = red8(cupp);
        n2 = a2v * n2 + 2.0f * a * cup + cu * cv;      // ||S_t||_F^2 recurrence
        if (j == 0) { wsv[PADW(r)] = w_r; hs[PADW(r)] = h_r; }

        // commit staged rows
        if (tid < 32) {
            ((float4*)kq[nbuf])[tid + (tid >> 2)] = pre;
        } else if (tid < 64) {
            int c4 = tid - 32;
            ((float4*)kq[nbuf])[40 + c4 + (c4 >> 2)] = pre;
        } else if (tid < 96) {
            int c4 = tid - 64;
            ((float4*)xr[nbuf])[c4 + (c4 >> 2)] = pre;
        }
        __syncthreads();                               // barrier 2

        // ---- phase 6 (row side): g = S w; rank-3 A; S, M updates; y = M q ----
        float ww[16];
        {
            const float4* w4 = (const float4*)wsv;
            #pragma unroll
            for (int m = 0; m < 4; ++m) {
                float4 a4 = w4[5 * j + m];
                ww[4*m+0] = a4.x; ww[4*m+1] = a4.y;
                ww[4*m+2] = a4.z; ww[4*m+3] = a4.w;
            }
        }
        float gp = 0.f;
        #pragma unroll
        for (int i = 0; i < 16; ++i) gp = fmaf(S[i], ww[i], gp);
        const float g_r = red8(gp);

        const float rho = a2v * g_r + a * cu * p_r + (a * cup + cv * cu) * u_r;
        const float sig = a2v * p_r + a * cv * u_r;
        const float tau = a2v * u_r;
        const float nrm = sqrtf(fmaxf(n2, 0.f)) + 1e-6f;
        const float rn  = 1.0f / nrm;
        const float c1  = -0.015f * rn;         // 0.99M - 0.01*(1.5 S/n - 0.5 A/n^3)
        const float c2  = 0.005f * rn * rn * rn;

        float yp = 0.f;
        // two 8-col halves: re-read k, read h, q; caps live VGPRs
        #pragma unroll
        for (int half = 0; half < 2; ++half) {
            const float4* k4 = (const float4*)kqb;
            const float4* h4 = (const float4*)hs;
            const float4* q4 = (const float4*)(kqb + 160);
            #pragma unroll
            for (int m2 = 0; m2 < 2; ++m2) {
                int m = half * 2 + m2;
                float4 kv4 = k4[5 * j + m];
                float4 hv4 = h4[5 * j + m];
                float4 qv4 = q4[5 * j + m];
                float kk[4] = {kv4.x, kv4.y, kv4.z, kv4.w};
                float hh[4] = {hv4.x, hv4.y, hv4.z, hv4.w};
                float qq[4] = {qv4.x, qv4.y, qv4.z, qv4.w};
                #pragma unroll
                for (int l = 0; l < 4; ++l) {
                    int i = 4 * m + l;
                    S[i] = fmaf(a, S[i], u_r * kk[l]);
                    A[i] = fmaf(a3v, A[i],
                                fmaf(rho, kk[l], fmaf(sig, ww[i], tau * hh[l])));
                    M[i] = fmaf(0.99f, M[i], fmaf(c1, S[i], c2 * A[i]));
                    yp   = fmaf(M[i], qq[l], yp);
                }
            }
        }
        const float y_r = red8(yp);
        if (j == 0) ys[base + (size_t)t * DD + r] = y_r;
    }
}

// ---------------- epilogue: out = ys @ Wout^T + bout ---------------------------
__global__ __launch_bounds__(128) void epilogue_kernel(
        const float* __restrict__ ys, const float* __restrict__ WoutT,
        const float* __restrict__ bout, float* __restrict__ out) {
    const int row0 = blockIdx.x * 4;
    const int e = threadIdx.x;
    __shared__ float yr[4][DD];
    #pragma unroll
    for (int rr = 0; rr < 4; ++rr)
        yr[rr][e] = ys[(size_t)(row0 + rr) * DD + e];
    __syncthreads();
    float acc[4] = {0,0,0,0};
    #pragma unroll 4
    for (int d = 0; d < DD; ++d) {
        float w = WoutT[d * DD + e];
        #pragma unroll
        for (int rr = 0; rr < 4; ++rr) acc[rr] = fmaf(yr[rr][d], w, acc[rr]);
    }
    const float bo = bout[e];
    #pragma unroll
    for (int rr = 0; rr < 4; ++rr)
        out[(size_t)(row0 + rr) * DD + e] = acc[rr] + bo;
}

extern "C" void kernel_launch(void* const* d_in, const int* in_sizes, int n_in,
                              void* d_out, int out_size, void* d_ws, size_t ws_size,
                              hipStream_t stream) {
    const float* x        = (const float*)d_in[0];
    const float* Wq       = (const float*)d_in[1];
    const float* Wk       = (const float*)d_in[2];
    const float* P0       = (const float*)d_in[3];
    const float* M0       = (const float*)d_in[4];
    const float* S0       = (const float*)d_in[5];
    const float* log_gain = (const float*)d_in[6];
    const float* coeffs   = (const float*)d_in[7];
    const float* Wout     = (const float*)d_in[8];
    const float* bout     = (const float*)d_in[9];
    float* out = (float*)d_out;

    float* ws    = (float*)d_ws;
    float* WqT   = ws;                      // 16384
    float* WkT   = ws + 16384;              // 16384
    float* WoutT = ws + 32768;              // 16384
    float* kphi  = ws + 49152;              // B*L*D each below
    float* qphi  = kphi + (size_t)BB * LL * DD;
    float* ysb   = qphi + (size_t)BB * LL * DD;

    hipLaunchKernelGGL(transpose3_kernel, dim3(3), dim3(256), 0, stream,
                       Wq, Wk, Wout, WqT, WkT, WoutT);
    hipLaunchKernelGGL(prologue_kernel, dim3(BB * LL / 4), dim3(128), 0, stream,
                       x, WqT, WkT, P0, log_gain, coeffs, kphi, qphi);
    hipLaunchKernelGGL(scan_kernel, dim3(BB), dim3(1024), 0, stream,
                       kphi, qphi, x, M0, S0, ysb);
    hipLaunchKernelGGL(epilogue_kernel, dim3(BB * LL / 4), dim3(128), 0, stream,
                       ysb, WoutT, bout, out);
}

// Round 6
// 4896.445 us; speedup vs baseline: 1.0018x; 1.0018x over previous
//
#include <hip/hip_runtime.h>

#define BB 16
#define LL 512
#define DD 128

// padded word index for exchanged vectors: +4 words per 16-word chunk ->
// the 8 j-lanes' float4 reads cover all 8 bank-groups (conflict-free)
#define PADW(c) ((c) + (((c) >> 4) << 2))

// 8-lane all-reduce sum (octet = DPP half-row), pure VALU:
// quad xor1, quad xor2, then half-row mirror pairs the two quads.
__device__ __forceinline__ float red8(float v) {
    v += __int_as_float(__builtin_amdgcn_update_dpp(
            0, __float_as_int(v), 0xB1, 0xF, 0xF, true));
    v += __int_as_float(__builtin_amdgcn_update_dpp(
            0, __float_as_int(v), 0x4E, 0xF, 0xF, true));
    v += __int_as_float(__builtin_amdgcn_update_dpp(
            0, __float_as_int(v), 0x141, 0xF, 0xF, true));
    return v;
}

// ---------------- transpose Wq, Wk, Wout (once per call, tiny) ----------------
__global__ void transpose3_kernel(const float* __restrict__ Wq,
                                  const float* __restrict__ Wk,
                                  const float* __restrict__ Wout,
                                  float* __restrict__ WqT,
                                  float* __restrict__ WkT,
                                  float* __restrict__ WoutT) {
    const float* src; float* dst;
    if (blockIdx.x == 0)      { src = Wq;   dst = WqT;   }
    else if (blockIdx.x == 1) { src = Wk;   dst = WkT;   }
    else                      { src = Wout; dst = WoutT; }
    for (int idx = threadIdx.x; idx < DD * DD; idx += blockDim.x) {
        int r = idx >> 7, c = idx & 127;
        dst[c * DD + r] = src[idx];
    }
}

// ---------------- prologue: q/k projections, k-normalize, P0 rotation, poly ----
__global__ __launch_bounds__(128) void prologue_kernel(
        const float* __restrict__ x, const float* __restrict__ WqT,
        const float* __restrict__ WkT, const float* __restrict__ P0,
        const float* __restrict__ log_gain, const float* __restrict__ coeffs,
        float* __restrict__ kphi, float* __restrict__ qphi) {
    const int row0 = blockIdx.x * 4;
    const int e = threadIdx.x;
    __shared__ float xs[4][DD];
    __shared__ float qrow[4][DD];
    __shared__ float wred[4][2];

    #pragma unroll
    for (int rr = 0; rr < 4; ++rr)
        xs[rr][e] = x[(size_t)(row0 + rr) * DD + e];
    __syncthreads();

    float aq[4] = {0,0,0,0}, ak[4] = {0,0,0,0};
    #pragma unroll 4
    for (int d = 0; d < DD; ++d) {
        float wq = WqT[d * DD + e];
        float wk = WkT[d * DD + e];
        #pragma unroll
        for (int rr = 0; rr < 4; ++rr) {
            float xv = xs[rr][d];
            aq[rr] = fmaf(xv, wq, aq[rr]);
            ak[rr] = fmaf(xv, wk, ak[rr]);
        }
    }
    const int lane = threadIdx.x & 63, wv = threadIdx.x >> 6;
    #pragma unroll
    for (int rr = 0; rr < 4; ++rr) {
        float s = ak[rr] * ak[rr];
        #pragma unroll
        for (int m = 1; m <= 32; m <<= 1) s += __shfl_xor(s, m);
        if (lane == 0) wred[rr][wv] = s;
    }
    __syncthreads();
    const float c0 = coeffs[0], c1v = coeffs[1];
    #pragma unroll
    for (int rr = 0; rr < 4; ++rr) {
        float s = wred[rr][0] + wred[rr][1];
        float kn = ak[rr] / fmaxf(sqrtf(s), 1e-12f);
        kphi[(size_t)(row0 + rr) * DD + e] = c0 * kn + c1v * kn * kn;
        qrow[rr][e] = aq[rr];
    }
    __syncthreads();
    float acc[4] = {0,0,0,0};
    #pragma unroll 4
    for (int d = 0; d < DD; ++d) {
        float pv = P0[d * DD + e];
        #pragma unroll
        for (int rr = 0; rr < 4; ++rr) acc[rr] = fmaf(qrow[rr][d], pv, acc[rr]);
    }
    const float g = expf(log_gain[e]);
    #pragma unroll
    for (int rr = 0; rr < 4; ++rr) {
        float qa = tanhf(g * acc[rr]);
        qphi[(size_t)(row0 + rr) * DD + e] = c0 * qa + c1v * qa * qa;
    }
}

// ---------------- main sequential scan: one block per batch --------------------
// 1024 threads = 16 waves = 4 waves/SIMD. amdgpu_waves_per_eu(4,4) pins exactly
// one block/CU so the allocator gets (and uses) the full 128-VGPR budget —
// launch_bounds(1024,4) alone let the compiler squeeze to 64 VGPRs and shuffle
// the 64-float state through AGPRs (R1/R5: ~4.8 ms). Thread (r = tid>>3,
// j = tid&7): row r x cols [16j,16j+16) of S, A, M, plus ST[r][c] = S[c][r].
// All reductions are 8-lane DPP butterflies. Exchanged vectors in bank-padded
// LDS. A = S S^T S via exact rank-3 recurrence; ||S||_F^2 via scalar
// recurrence. Phase 6 runs in two 8-col halves to cap live temporaries.
__global__ __launch_bounds__(1024)
__attribute__((amdgpu_waves_per_eu(4, 4)))
void scan_kernel(
        const float* __restrict__ kphi, const float* __restrict__ qphi,
        const float* __restrict__ x, const float* __restrict__ M0,
        const float* __restrict__ S0, float* __restrict__ ys) {
    const int b   = blockIdx.x;
    const int tid = threadIdx.x;
    const int j   = tid & 7;
    const int r   = tid >> 3;

    __shared__ __align__(16) float kq[2][320];   // k at PADW(c), q at 160+PADW(c)
    __shared__ __align__(16) float xr[2][160];
    __shared__ __align__(16) float us[160], ps[160], wsv[160], hs[160];
    __shared__ float red[DD];
    __shared__ float n2sh[2];

    float S[16], ST[16], A[16], M[16];
    {
        const float4* S04 = (const float4*)S0;
        const float4* M04 = (const float4*)M0;
        #pragma unroll
        for (int m = 0; m < 4; ++m) {
            int f4 = r * 32 + 4 * j + m;
            float4 s4 = S04[f4], m4 = M04[f4];
            int i = 4 * m;
            S[i+0] = s4.x; S[i+1] = s4.y; S[i+2] = s4.z; S[i+3] = s4.w;
            M[i+0] = m4.x; M[i+1] = m4.y; M[i+2] = m4.z; M[i+3] = m4.w;
        }
        #pragma unroll
        for (int cl = 0; cl < 16; ++cl)
            ST[cl] = S0[(size_t)(16 * j + cl) * DD + r];
        #pragma unroll
        for (int i = 0; i < 16; ++i) A[i] = 0.f;     // exact when S0 == 0
    }

    // ||S0||^2 block reduction + stage t=0 vectors
    float sp = 0.f;
    #pragma unroll
    for (int i = 0; i < 16; ++i) sp = fmaf(S[i], S[i], sp);
    sp = red8(sp);
    if (j == 0) red[r] = sp;

    const size_t base = (size_t)b * LL * DD;
    if (tid < 32) {
        ((float4*)kq[0])[tid + (tid >> 2)] = *(const float4*)(kphi + base + 4 * tid);
    } else if (tid < 64) {
        int c4 = tid - 32;
        ((float4*)kq[0])[40 + c4 + (c4 >> 2)] = *(const float4*)(qphi + base + 4 * c4);
    } else if (tid < 96) {
        int c4 = tid - 64;
        ((float4*)xr[0])[c4 + (c4 >> 2)] = *(const float4*)(x + base + 4 * c4);
    }
    __syncthreads();
    if (tid < 128) {
        float s = red[tid];
        #pragma unroll
        for (int m = 1; m <= 32; m <<= 1) s += __shfl_xor(s, m);
        if ((tid & 63) == 0) n2sh[tid >> 6] = s;
    }
    __syncthreads();
    float n2 = n2sh[0] + n2sh[1];

    const float a = 0.9f, a2v = 0.81f, a3v = 0.729f;

    for (int t = 0; t < LL; ++t) {
        const int buf = t & 1, nbuf = buf ^ 1;
        const float* kqb = kq[buf];

        // ---- phase 2 (row side): pred = M k, p = S v, cv = v.v ----
        float pr = 0.f, pp = 0.f, cvp = 0.f;
        {
            const float4* k4 = (const float4*)kqb;
            #pragma unroll
            for (int m = 0; m < 4; ++m) {
                float4 v4 = k4[5 * j + m];
                float vv[4] = {v4.x, v4.y, v4.z, v4.w};
                #pragma unroll
                for (int l = 0; l < 4; ++l) {
                    int i = 4 * m + l;
                    pr  = fmaf(M[i], vv[l], pr);
                    pp  = fmaf(S[i], vv[l], pp);
                    cvp = fmaf(vv[l], vv[l], cvp);
                }
            }
        }
        pr = red8(pr); pp = red8(pp);
        const float cv  = red8(cvp);
        const float x_r = xr[buf][PADW(r)];
        const float u_r = pr - x_r;     // err
        const float p_r = pp;
        if (j == 0) { us[PADW(r)] = u_r; ps[PADW(r)] = p_r; }
        __syncthreads();                               // barrier 1

        // staging loads for t+1 (in flight across phase 4)
        const int tn = (t + 1 < LL) ? (t + 1) : (LL - 1);
        const size_t nb = base + (size_t)tn * DD;
        float4 pre;
        if (tid < 32)       pre = *(const float4*)(kphi + nb + 4 * tid);
        else if (tid < 64)  pre = *(const float4*)(qphi + nb + 4 * (tid - 32));
        else if (tid < 96)  pre = *(const float4*)(x + nb + 4 * (tid - 64));

        // ---- phase 4 (col side): w = S^T u, h = S^T p, dots; ST update ----
        const float v_r = kqb[PADW(r)];
        float wp = 0.f, hp = 0.f, cuup = 0.f, cupp = 0.f;
        {
            const float4* u4 = (const float4*)us;
            const float4* p4 = (const float4*)ps;
            #pragma unroll
            for (int m = 0; m < 4; ++m) {
                float4 a4 = u4[5 * j + m], b4 = p4[5 * j + m];
                float uu[4] = {a4.x, a4.y, a4.z, a4.w};
                float pa[4] = {b4.x, b4.y, b4.z, b4.w};
                #pragma unroll
                for (int l = 0; l < 4; ++l) {
                    int i = 4 * m + l;
                    float st = ST[i];
                    wp   = fmaf(st, uu[l], wp);
                    hp   = fmaf(st, pa[l], hp);
                    cuup = fmaf(uu[l], uu[l], cuup);
                    cupp = fmaf(uu[l], pa[l], cupp);
                    ST[i] = fmaf(a, st, v_r * uu[l]);   // old st used above only
                }
            }
        }
        const float w_r = red8(wp);
        const float h_r = red8(hp);
        const float cu  = red8(cuup);
        const float cup = red8(cupp);
        n2 = a2v * n2 + 2.0f * a * cup + cu * cv;      // ||S_t||_F^2 recurrence
        if (j == 0) { wsv[PADW(r)] = w_r; hs[PADW(r)] = h_r; }

        // commit staged rows
        if (tid < 32) {
            ((float4*)kq[nbuf])[tid + (tid >> 2)] = pre;
        } else if (tid < 64) {
            int c4 = tid - 32;
            ((float4*)kq[nbuf])[40 + c4 + (c4 >> 2)] = pre;
        } else if (tid < 96) {
            int c4 = tid - 64;
            ((float4*)xr[nbuf])[c4 + (c4 >> 2)] = pre;
        }
        __syncthreads();                               // barrier 2

        // ---- phase 6 (row side): g = S w; rank-3 A; S, M updates; y = M q ----
        float ww[16];
        {
            const float4* w4 = (const float4*)wsv;
            #pragma unroll
            for (int m = 0; m < 4; ++m) {
                float4 a4 = w4[5 * j + m];
                ww[4*m+0] = a4.x; ww[4*m+1] = a4.y;
                ww[4*m+2] = a4.z; ww[4*m+3] = a4.w;
            }
        }
        float gp = 0.f;
        #pragma unroll
        for (int i = 0; i < 16; ++i) gp = fmaf(S[i], ww[i], gp);
        const float g_r = red8(gp);

        const float rho = a2v * g_r + a * cu * p_r + (a * cup + cv * cu) * u_r;
        const float sig = a2v * p_r + a * cv * u_r;
        const float tau = a2v * u_r;
        const float nrm = sqrtf(fmaxf(n2, 0.f)) + 1e-6f;
        const float rn  = 1.0f / nrm;
        const float c1  = -0.015f * rn;         // 0.99M - 0.01*(1.5 S/n - 0.5 A/n^3)
        const float c2  = 0.005f * rn * rn * rn;

        float yp = 0.f;
        // two 8-col halves: re-read k, read h, q; caps live VGPRs
        #pragma unroll
        for (int half = 0; half < 2; ++half) {
            const float4* k4 = (const float4*)kqb;
            const float4* h4 = (const float4*)hs;
            const float4* q4 = (const float4*)(kqb + 160);
            #pragma unroll
            for (int m2 = 0; m2 < 2; ++m2) {
                int m = half * 2 + m2;
                float4 kv4 = k4[5 * j + m];
                float4 hv4 = h4[5 * j + m];
                float4 qv4 = q4[5 * j + m];
                float kk[4] = {kv4.x, kv4.y, kv4.z, kv4.w};
                float hh[4] = {hv4.x, hv4.y, hv4.z, hv4.w};
                float qq[4] = {qv4.x, qv4.y, qv4.z, qv4.w};
                #pragma unroll
                for (int l = 0; l < 4; ++l) {
                    int i = 4 * m + l;
                    S[i] = fmaf(a, S[i], u_r * kk[l]);
                    A[i] = fmaf(a3v, A[i],
                                fmaf(rho, kk[l], fmaf(sig, ww[i], tau * hh[l])));
                    M[i] = fmaf(0.99f, M[i], fmaf(c1, S[i], c2 * A[i]));
                    yp   = fmaf(M[i], qq[l], yp);
                }
            }
        }
        const float y_r = red8(yp);
        if (j == 0) ys[base + (size_t)t * DD + r] = y_r;
    }
}

// ---------------- epilogue: out = ys @ Wout^T + bout ---------------------------
__global__ __launch_bounds__(128) void epilogue_kernel(
        const float* __restrict__ ys, const float* __restrict__ WoutT,
        const float* __restrict__ bout, float* __restrict__ out) {
    const int row0 = blockIdx.x * 4;
    const int e = threadIdx.x;
    __shared__ float yr[4][DD];
    #pragma unroll
    for (int rr = 0; rr < 4; ++rr)
        yr[rr][e] = ys[(size_t)(row0 + rr) * DD + e];
    __syncthreads();
    float acc[4] = {0,0,0,0};
    #pragma unroll 4
    for (int d = 0; d < DD; ++d) {
        float w = WoutT[d * DD + e];
        #pragma unroll
        for (int rr = 0; rr < 4; ++rr) acc[rr] = fmaf(yr[rr][d], w, acc[rr]);
    }
    const float bo = bout[e];
    #pragma unroll
    for (int rr = 0; rr < 4; ++rr)
        out[(size_t)(row0 + rr) * DD + e] = acc[rr] + bo;
}

extern "C" void kernel_launch(void* const* d_in, const int* in_sizes, int n_in,
                              void* d_out, int out_size, void* d_ws, size_t ws_size,
                              hipStream_t stream) {
    const float* x        = (const float*)d_in[0];
    const float* Wq       = (const float*)d_in[1];
    const float* Wk       = (const float*)d_in[2];
    const float* P0       = (const float*)d_in[3];
    const float* M0       = (const float*)d_in[4];
    const float* S0       = (const float*)d_in[5];
    const float* log_gain = (const float*)d_in[6];
    const float* coeffs   = (const float*)d_in[7];
    const float* Wout     = (const float*)d_in[8];
    const float* bout     = (const float*)d_in[9];
    float* out = (float*)d_out;

    float* ws    = (float*)d_ws;
    float* WqT   = ws;                      // 16384
    float* WkT   = ws + 16384;              // 16384
    float* WoutT = ws + 32768;              // 16384
    float* kphi  = ws + 49152;              // B*L*D each below
    float* qphi  = kphi + (size_t)BB * LL * DD;
    float* ysb   = qphi + (size_t)BB * LL * DD;

    hipLaunchKernelGGL(transpose3_kernel, dim3(3), dim3(256), 0, stream,
                       Wq, Wk, Wout, WqT, WkT, WoutT);
    hipLaunchKernelGGL(prologue_kernel, dim3(BB * LL / 4), dim3(128), 0, stream,
                       x, WqT, WkT, P0, log_gain, coeffs, kphi, qphi);
    hipLaunchKernelGGL(scan_kernel, dim3(BB), dim3(1024), 0, stream,
                       kphi, qphi, x, M0, S0, ysb);
    hipLaunchKernelGGL(epilogue_kernel, dim3(BB * LL / 4), dim3(128), 0, stream,
                       ysb, WoutT, bout, out);
}

// Round 7
// 3176.089 us; speedup vs baseline: 1.5444x; 1.5417x over previous
//
#include <hip/hip_runtime.h>

#define BB 16
#define LL 512
#define DD 128

// padded word index for exchanged vectors: +4 words per 16-word chunk ->
// the 8 j-lanes' float4 reads cover all 8 bank-groups (conflict-free)
#define PADW(c) ((c) + (((c) >> 4) << 2))

// 8-lane all-reduce sum (lanes within a DPP half-row), pure VALU:
// quad xor1, quad xor2, then half-row mirror pairs the two quads.
__device__ __forceinline__ float red8(float v) {
    v += __int_as_float(__builtin_amdgcn_update_dpp(
            0, __float_as_int(v), 0xB1, 0xF, 0xF, true));
    v += __int_as_float(__builtin_amdgcn_update_dpp(
            0, __float_as_int(v), 0x4E, 0xF, 0xF, true));
    v += __int_as_float(__builtin_amdgcn_update_dpp(
            0, __float_as_int(v), 0x141, 0xF, 0xF, true));
    return v;
}

// ---------------- transpose Wq, Wk, Wout (once per call, tiny) ----------------
__global__ void transpose3_kernel(const float* __restrict__ Wq,
                                  const float* __restrict__ Wk,
                                  const float* __restrict__ Wout,
                                  float* __restrict__ WqT,
                                  float* __restrict__ WkT,
                                  float* __restrict__ WoutT) {
    const float* src; float* dst;
    if (blockIdx.x == 0)      { src = Wq;   dst = WqT;   }
    else if (blockIdx.x == 1) { src = Wk;   dst = WkT;   }
    else                      { src = Wout; dst = WoutT; }
    for (int idx = threadIdx.x; idx < DD * DD; idx += blockDim.x) {
        int r = idx >> 7, c = idx & 127;
        dst[c * DD + r] = src[idx];
    }
}

// ---------------- prologue: q/k projections, k-normalize, P0 rotation, poly ----
__global__ __launch_bounds__(128) void prologue_kernel(
        const float* __restrict__ x, const float* __restrict__ WqT,
        const float* __restrict__ WkT, const float* __restrict__ P0,
        const float* __restrict__ log_gain, const float* __restrict__ coeffs,
        float* __restrict__ kphi, float* __restrict__ qphi) {
    const int row0 = blockIdx.x * 4;
    const int e = threadIdx.x;
    __shared__ float xs[4][DD];
    __shared__ float qrow[4][DD];
    __shared__ float wred[4][2];

    #pragma unroll
    for (int rr = 0; rr < 4; ++rr)
        xs[rr][e] = x[(size_t)(row0 + rr) * DD + e];
    __syncthreads();

    float aq[4] = {0,0,0,0}, ak[4] = {0,0,0,0};
    #pragma unroll 4
    for (int d = 0; d < DD; ++d) {
        float wq = WqT[d * DD + e];
        float wk = WkT[d * DD + e];
        #pragma unroll
        for (int rr = 0; rr < 4; ++rr) {
            float xv = xs[rr][d];
            aq[rr] = fmaf(xv, wq, aq[rr]);
            ak[rr] = fmaf(xv, wk, ak[rr]);
        }
    }
    const int lane = threadIdx.x & 63, wv = threadIdx.x >> 6;
    #pragma unroll
    for (int rr = 0; rr < 4; ++rr) {
        float s = ak[rr] * ak[rr];
        #pragma unroll
        for (int m = 1; m <= 32; m <<= 1) s += __shfl_xor(s, m);
        if (lane == 0) wred[rr][wv] = s;
    }
    __syncthreads();
    const float c0 = coeffs[0], c1v = coeffs[1];
    #pragma unroll
    for (int rr = 0; rr < 4; ++rr) {
        float s = wred[rr][0] + wred[rr][1];
        float kn = ak[rr] / fmaxf(sqrtf(s), 1e-12f);
        kphi[(size_t)(row0 + rr) * DD + e] = c0 * kn + c1v * kn * kn;
        qrow[rr][e] = aq[rr];
    }
    __syncthreads();
    float acc[4] = {0,0,0,0};
    #pragma unroll 4
    for (int d = 0; d < DD; ++d) {
        float pv = P0[d * DD + e];
        #pragma unroll
        for (int rr = 0; rr < 4; ++rr) acc[rr] = fmaf(qrow[rr][d], pv, acc[rr]);
    }
    const float g = expf(log_gain[e]);
    #pragma unroll
    for (int rr = 0; rr < 4; ++rr) {
        float qa = tanhf(g * acc[rr]);
        qphi[(size_t)(row0 + rr) * DD + e] = c0 * qa + c1v * qa * qa;
    }
}

// ---------------- main sequential scan: one block per batch --------------------
// 512 threads, amdgpu_waves_per_eu(2,2): CAP occupancy at 2 waves/EU so the
// allocator gets 256 regs/wave and keeps the full 128-float state (S/ST/A/M
// x32) in ARCH VGPRs — launch_bounds(512,2) only set a *minimum*, the
// compiler targeted higher occupancy and split 128 arch + AGPR overflow,
// paying v_accvgpr copies on every state touch (R3: 4800 VALU-issue
// cyc/step vs ~1400 source-level). Thread (g = tid>>3, j = tid&7): rows
// {2g,2g+1} x cols [16j,16j+16) of S, A, M; plus ST tile. 8-lane DPP
// butterflies for reductions; bank-padded LDS for exchanged vectors.
// A = S S^T S via exact rank-3 recurrence; ||S||_F^2 via scalar recurrence.
__global__ __attribute__((amdgpu_waves_per_eu(2, 2))) __launch_bounds__(512)
void scan_kernel(
        const float* __restrict__ kphi, const float* __restrict__ qphi,
        const float* __restrict__ x, const float* __restrict__ M0,
        const float* __restrict__ S0, float* __restrict__ ys) {
    const int b   = blockIdx.x;
    const int tid = threadIdx.x;
    const int j   = tid & 7;
    const int g   = tid >> 3;
    const int r0  = 2 * g;

    __shared__ __align__(16) float kq[2][320];   // k at PADW(c), q at 160+PADW(c)
    __shared__ __align__(16) float xr[2][160];
    __shared__ __align__(16) float us[160], ps[160], wsv[160], hs[160];
    __shared__ float red[64];
    __shared__ float n2sh;

    float S[32], ST[32], A[32], M[32];
    {
        const float4* S04 = (const float4*)S0;
        const float4* M04 = (const float4*)M0;
        #pragma unroll
        for (int rl = 0; rl < 2; ++rl)
            #pragma unroll
            for (int m = 0; m < 4; ++m) {
                int f4 = (r0 + rl) * 32 + 4 * j + m;
                float4 s4 = S04[f4], m4 = M04[f4];
                int i = rl * 16 + 4 * m;
                S[i+0] = s4.x; S[i+1] = s4.y; S[i+2] = s4.z; S[i+3] = s4.w;
                M[i+0] = m4.x; M[i+1] = m4.y; M[i+2] = m4.z; M[i+3] = m4.w;
            }
        #pragma unroll
        for (int rl = 0; rl < 2; ++rl)
            #pragma unroll
            for (int cl = 0; cl < 16; ++cl)
                ST[rl*16+cl] = S0[(size_t)(16*j + cl) * DD + r0 + rl];
        #pragma unroll
        for (int i = 0; i < 32; ++i) A[i] = 0.f;   // exact when S0 == 0
    }

    // ||S0||^2 block reduction + stage t=0 vectors
    float sp = 0.f;
    #pragma unroll
    for (int i = 0; i < 32; ++i) sp = fmaf(S[i], S[i], sp);
    sp = red8(sp);
    if (j == 0) red[g] = sp;

    const size_t base = (size_t)b * LL * DD;
    if (tid < 32) {
        ((float4*)kq[0])[tid + (tid >> 2)] = *(const float4*)(kphi + base + 4 * tid);
    } else if (tid < 64) {
        int c4 = tid - 32;
        ((float4*)kq[0])[40 + c4 + (c4 >> 2)] = *(const float4*)(qphi + base + 4 * c4);
    } else if (tid < 96) {
        int c4 = tid - 64;
        ((float4*)xr[0])[c4 + (c4 >> 2)] = *(const float4*)(x + base + 4 * c4);
    }
    __syncthreads();
    if (tid < 64) {
        float s = red[tid];
        #pragma unroll
        for (int m = 1; m <= 32; m <<= 1) s += __shfl_xor(s, m);
        if (tid == 0) n2sh = s;
    }
    __syncthreads();
    float n2 = n2sh;

    const float a = 0.9f, a2v = 0.81f, a3v = 0.729f;

    for (int t = 0; t < LL; ++t) {
        const int buf = t & 1, nbuf = buf ^ 1;
        const float* kqb = kq[buf];

        // ---- phase 2 (row side): pred = M k, p = S v, cv = v.v ----
        float kk[16];
        {
            const float4* k4 = (const float4*)kqb;
            #pragma unroll
            for (int m = 0; m < 4; ++m) {
                float4 v4 = k4[5 * j + m];
                kk[4*m+0] = v4.x; kk[4*m+1] = v4.y;
                kk[4*m+2] = v4.z; kk[4*m+3] = v4.w;
            }
        }
        float pr0 = 0.f, pr1 = 0.f, pp0 = 0.f, pp1 = 0.f, cvp = 0.f;
        #pragma unroll
        for (int cl = 0; cl < 16; ++cl) {
            float kv = kk[cl];
            pr0 = fmaf(M[cl],      kv, pr0);
            pr1 = fmaf(M[16 + cl], kv, pr1);
            pp0 = fmaf(S[cl],      kv, pp0);
            pp1 = fmaf(S[16 + cl], kv, pp1);
            cvp = fmaf(kv, kv, cvp);
        }
        pr0 = red8(pr0); pr1 = red8(pr1);
        pp0 = red8(pp0); pp1 = red8(pp1);
        const float cv = red8(cvp);
        const float2 xv = *(const float2*)&xr[buf][PADW(r0)];
        const float u0 = pr0 - xv.x, u1 = pr1 - xv.y;
        const float p0 = pp0, p1 = pp1;
        if (j == 0) {
            *(float2*)&us[PADW(r0)] = make_float2(u0, u1);
            *(float2*)&ps[PADW(r0)] = make_float2(p0, p1);
        }
        __syncthreads();                               // barrier 1

        // staging loads for t+1 (in flight across phase 4)
        const int tn = (t + 1 < LL) ? (t + 1) : (LL - 1);
        const size_t nb = base + (size_t)tn * DD;
        float4 pre;
        if (tid < 32)       pre = *(const float4*)(kphi + nb + 4 * tid);
        else if (tid < 64)  pre = *(const float4*)(qphi + nb + 4 * (tid - 32));
        else if (tid < 96)  pre = *(const float4*)(x + nb + 4 * (tid - 64));

        // ---- phase 4 (col side): w = S^T u, h = S^T p, dots; ST update ----
        float uu[16], pa[16];
        {
            const float4* u4 = (const float4*)us;
            const float4* p4 = (const float4*)ps;
            #pragma unroll
            for (int m = 0; m < 4; ++m) {
                float4 a4 = u4[5 * j + m], b4 = p4[5 * j + m];
                uu[4*m+0] = a4.x; uu[4*m+1] = a4.y;
                uu[4*m+2] = a4.z; uu[4*m+3] = a4.w;
                pa[4*m+0] = b4.x; pa[4*m+1] = b4.y;
                pa[4*m+2] = b4.z; pa[4*m+3] = b4.w;
            }
        }
        const float2 vc = *(const float2*)&kqb[PADW(r0)];
        float w0 = 0.f, w1 = 0.f, h0 = 0.f, h1 = 0.f, cuup = 0.f, cupp = 0.f;
        #pragma unroll
        for (int cl = 0; cl < 16; ++cl) {
            float uv = uu[cl], pv = pa[cl];
            float st0 = ST[cl], st1 = ST[16 + cl];
            w0 = fmaf(st0, uv, w0);  w1 = fmaf(st1, uv, w1);
            h0 = fmaf(st0, pv, h0);  h1 = fmaf(st1, pv, h1);
            cuup = fmaf(uv, uv, cuup);
            cupp = fmaf(uv, pv, cupp);
            ST[cl]      = fmaf(a, st0, vc.x * uv);     // old st used above only
            ST[16 + cl] = fmaf(a, st1, vc.y * uv);
        }
        w0 = red8(w0); w1 = red8(w1); h0 = red8(h0); h1 = red8(h1);
        const float cu  = red8(cuup);
        const float cup = red8(cupp);
        n2 = a2v * n2 + 2.0f * a * cup + cu * cv;      // ||S_t||_F^2 recurrence
        if (j == 0) {
            *(float2*)&wsv[PADW(r0)] = make_float2(w0, w1);
            *(float2*)&hs[PADW(r0)]  = make_float2(h0, h1);
        }
        // commit staged rows
        if (tid < 32) {
            ((float4*)kq[nbuf])[tid + (tid >> 2)] = pre;
        } else if (tid < 64) {
            int c4 = tid - 32;
            ((float4*)kq[nbuf])[40 + c4 + (c4 >> 2)] = pre;
        } else if (tid < 96) {
            int c4 = tid - 64;
            ((float4*)xr[nbuf])[c4 + (c4 >> 2)] = pre;
        }
        __syncthreads();                               // barrier 2

        // ---- phase 6 (row side): g = S w; rank-3 A; S, M updates; y = M q ----
        float ww[16], hh[16], qq[16];
        {
            const float4* w4 = (const float4*)wsv;
            const float4* h4 = (const float4*)hs;
            const float4* q4 = (const float4*)(kqb + 160);
            #pragma unroll
            for (int m = 0; m < 4; ++m) {
                float4 a4 = w4[5 * j + m], b4 = h4[5 * j + m], c4v = q4[5 * j + m];
                ww[4*m+0] = a4.x;  ww[4*m+1] = a4.y;
                ww[4*m+2] = a4.z;  ww[4*m+3] = a4.w;
                hh[4*m+0] = b4.x;  hh[4*m+1] = b4.y;
                hh[4*m+2] = b4.z;  hh[4*m+3] = b4.w;
                qq[4*m+0] = c4v.x; qq[4*m+1] = c4v.y;
                qq[4*m+2] = c4v.z; qq[4*m+3] = c4v.w;
            }
        }
        float g0 = 0.f, g1 = 0.f;
        #pragma unroll
        for (int cl = 0; cl < 16; ++cl) {
            g0 = fmaf(S[cl],      ww[cl], g0);
            g1 = fmaf(S[16 + cl], ww[cl], g1);
        }
        g0 = red8(g0); g1 = red8(g1);

        const float rho0 = a2v * g0 + a * cu * p0 + (a * cup + cv * cu) * u0;
        const float rho1 = a2v * g1 + a * cu * p1 + (a * cup + cv * cu) * u1;
        const float sg0  = a2v * p0 + a * cv * u0;
        const float sg1  = a2v * p1 + a * cv * u1;
        const float ta0  = a2v * u0, ta1 = a2v * u1;
        const float nrm  = sqrtf(fmaxf(n2, 0.f)) + 1e-6f;
        const float rn   = 1.0f / nrm;
        const float c1   = -0.015f * rn;        // 0.99M - 0.01*(1.5 S/n - 0.5 A/n^3)
        const float c2   = 0.005f * rn * rn * rn;

        float y0 = 0.f, y1 = 0.f;
        #pragma unroll
        for (int cl = 0; cl < 16; ++cl) {
            float kv = kk[cl], wv = ww[cl], hv = hh[cl], qv = qq[cl];
            S[cl]      = fmaf(a, S[cl],      u0 * kv);
            S[16 + cl] = fmaf(a, S[16 + cl], u1 * kv);
            A[cl]      = fmaf(a3v, A[cl],
                              fmaf(rho0, kv, fmaf(sg0, wv, ta0 * hv)));
            A[16 + cl] = fmaf(a3v, A[16 + cl],
                              fmaf(rho1, kv, fmaf(sg1, wv, ta1 * hv)));
            M[cl]      = fmaf(0.99f, M[cl],      fmaf(c1, S[cl],      c2 * A[cl]));
            M[16 + cl] = fmaf(0.99f, M[16 + cl], fmaf(c1, S[16 + cl], c2 * A[16 + cl]));
            y0 = fmaf(M[cl],      qv, y0);
            y1 = fmaf(M[16 + cl], qv, y1);
        }
        y0 = red8(y0); y1 = red8(y1);
        if (j == 0)
            *(float2*)(ys + base + (size_t)t * DD + r0) = make_float2(y0, y1);
    }
}

// ---------------- epilogue: out = ys @ Wout^T + bout ---------------------------
__global__ __launch_bounds__(128) void epilogue_kernel(
        const float* __restrict__ ys, const float* __restrict__ WoutT,
        const float* __restrict__ bout, float* __restrict__ out) {
    const int row0 = blockIdx.x * 4;
    const int e = threadIdx.x;
    __shared__ float yr[4][DD];
    #pragma unroll
    for (int rr = 0; rr < 4; ++rr)
        yr[rr][e] = ys[(size_t)(row0 + rr) * DD + e];
    __syncthreads();
    float acc[4] = {0,0,0,0};
    #pragma unroll 4
    for (int d = 0; d < DD; ++d) {
        float w = WoutT[d * DD + e];
        #pragma unroll
        for (int rr = 0; rr < 4; ++rr) acc[rr] = fmaf(yr[rr][d], w, acc[rr]);
    }
    const float bo = bout[e];
    #pragma unroll
    for (int rr = 0; rr < 4; ++rr)
        out[(size_t)(row0 + rr) * DD + e] = acc[rr] + bo;
}

extern "C" void kernel_launch(void* const* d_in, const int* in_sizes, int n_in,
                              void* d_out, int out_size, void* d_ws, size_t ws_size,
                              hipStream_t stream) {
    const float* x        = (const float*)d_in[0];
    const float* Wq       = (const float*)d_in[1];
    const float* Wk       = (const float*)d_in[2];
    const float* P0       = (const float*)d_in[3];
    const float* M0       = (const float*)d_in[4];
    const float* S0       = (const float*)d_in[5];
    const float* log_gain = (const float*)d_in[6];
    const float* coeffs   = (const float*)d_in[7];
    const float* Wout     = (const float*)d_in[8];
    const float* bout     = (const float*)d_in[9];
    float* out = (float*)d_out;

    float* ws    = (float*)d_ws;
    float* WqT   = ws;                      // 16384
    float* WkT   = ws + 16384;              // 16384
    float* WoutT = ws + 32768;              // 16384
    float* kphi  = ws + 49152;              // B*L*D each below
    float* qphi  = kphi + (size_t)BB * LL * DD;
    float* ysb   = qphi + (size_t)BB * LL * DD;

    hipLaunchKernelGGL(transpose3_kernel, dim3(3), dim3(256), 0, stream,
                       Wq, Wk, Wout, WqT, WkT, WoutT);
    hipLaunchKernelGGL(prologue_kernel, dim3(BB * LL / 4), dim3(128), 0, stream,
                       x, WqT, WkT, P0, log_gain, coeffs, kphi, qphi);
    hipLaunchKernelGGL(scan_kernel, dim3(BB), dim3(512), 0, stream,
                       kphi, qphi, x, M0, S0, ysb);
    hipLaunchKernelGGL(epilogue_kernel, dim3(BB * LL / 4), dim3(128), 0, stream,
                       ysb, WoutT, bout, out);
}

// Round 8
// 2038.469 us; speedup vs baseline: 2.4063x; 1.5581x over previous
//
#include <hip/hip_runtime.h>

#define BB 16
#define LL 512
#define DD 128
#define CH 16
#define NCH (LL / CH)

// 8-lane all-reduce sum (lanes within a DPP half-row), pure VALU:
// quad xor1, quad xor2, then half-row mirror pairs the two quads.
__device__ __forceinline__ float red8(float v) {
    v += __int_as_float(__builtin_amdgcn_update_dpp(
            0, __float_as_int(v), 0xB1, 0xF, 0xF, true));
    v += __int_as_float(__builtin_amdgcn_update_dpp(
            0, __float_as_int(v), 0x4E, 0xF, 0xF, true));
    v += __int_as_float(__builtin_amdgcn_update_dpp(
            0, __float_as_int(v), 0x141, 0xF, 0xF, true));
    return v;
}

#if defined(__has_attribute)
#  if __has_attribute(amdgpu_num_vgpr)
#    define SCAN_REGS __attribute__((amdgpu_waves_per_eu(2, 2), amdgpu_num_vgpr(256)))
#  else
#    define SCAN_REGS __attribute__((amdgpu_waves_per_eu(2, 2)))
#  endif
#else
#  define SCAN_REGS __attribute__((amdgpu_waves_per_eu(2, 2)))
#endif

// ---------------- transpose Wq, Wk, Wout (once per call, tiny) ----------------
__global__ void transpose3_kernel(const float* __restrict__ Wq,
                                  const float* __restrict__ Wk,
                                  const float* __restrict__ Wout,
                                  float* __restrict__ WqT,
                                  float* __restrict__ WkT,
                                  float* __restrict__ WoutT) {
    const float* src; float* dst;
    if (blockIdx.x == 0)      { src = Wq;   dst = WqT;   }
    else if (blockIdx.x == 1) { src = Wk;   dst = WkT;   }
    else                      { src = Wout; dst = WoutT; }
    for (int idx = threadIdx.x; idx < DD * DD; idx += blockDim.x) {
        int r = idx >> 7, c = idx & 127;
        dst[c * DD + r] = src[idx];
    }
}

// ---------------- prologue: q/k projections, k-normalize, P0 rotation, poly ----
__global__ __launch_bounds__(128) void prologue_kernel(
        const float* __restrict__ x, const float* __restrict__ WqT,
        const float* __restrict__ WkT, const float* __restrict__ P0,
        const float* __restrict__ log_gain, const float* __restrict__ coeffs,
        float* __restrict__ kphi, float* __restrict__ qphi) {
    const int row0 = blockIdx.x * 4;
    const int e = threadIdx.x;
    __shared__ float xs[4][DD];
    __shared__ float qrow[4][DD];
    __shared__ float wred[4][2];

    #pragma unroll
    for (int rr = 0; rr < 4; ++rr)
        xs[rr][e] = x[(size_t)(row0 + rr) * DD + e];
    __syncthreads();

    float aq[4] = {0,0,0,0}, ak[4] = {0,0,0,0};
    #pragma unroll 4
    for (int d = 0; d < DD; ++d) {
        float wq = WqT[d * DD + e];
        float wk = WkT[d * DD + e];
        #pragma unroll
        for (int rr = 0; rr < 4; ++rr) {
            float xv = xs[rr][d];
            aq[rr] = fmaf(xv, wq, aq[rr]);
            ak[rr] = fmaf(xv, wk, ak[rr]);
        }
    }
    const int lane = threadIdx.x & 63, wv = threadIdx.x >> 6;
    #pragma unroll
    for (int rr = 0; rr < 4; ++rr) {
        float s = ak[rr] * ak[rr];
        #pragma unroll
        for (int m = 1; m <= 32; m <<= 1) s += __shfl_xor(s, m);
        if (lane == 0) wred[rr][wv] = s;
    }
    __syncthreads();
    const float c0 = coeffs[0], c1v = coeffs[1];
    #pragma unroll
    for (int rr = 0; rr < 4; ++rr) {
        float s = wred[rr][0] + wred[rr][1];
        float kn = ak[rr] / fmaxf(sqrtf(s), 1e-12f);
        kphi[(size_t)(row0 + rr) * DD + e] = c0 * kn + c1v * kn * kn;
        qrow[rr][e] = aq[rr];
    }
    __syncthreads();
    float acc[4] = {0,0,0,0};
    #pragma unroll 4
    for (int d = 0; d < DD; ++d) {
        float pv = P0[d * DD + e];
        #pragma unroll
        for (int rr = 0; rr < 4; ++rr) acc[rr] = fmaf(qrow[rr][d], pv, acc[rr]);
    }
    const float g = expf(log_gain[e]);
    #pragma unroll
    for (int rr = 0; rr < 4; ++rr) {
        float qa = tanhf(g * acc[rr]);
        qphi[(size_t)(row0 + rr) * DD + e] = c0 * qa + c1v * qa * qa;
    }
}

// ---------------- main sequential scan: one block per batch --------------------
// 512 threads. CHUNKED LDS STAGING: k/q/x are bulk-copied into LDS in 16-step
// chunks (double-buffered) and ys is buffered in LDS, flushed once per chunk —
// so the steady-state per-step barriers have NO outstanding vmem and the
// compiler's mandatory `s_waitcnt vmcnt(0)` before each s_barrier is free.
// Thread (g = tid>>3, j = tid&7): rows {2g,2g+1}; interleaved column set
// col(m,l) = 4j + 32m + l (float4s {j+8m}) -> unpadded LDS vector reads are
// conflict-free (8 j-lanes hit 8 distinct bank-quads). ST holds the transpose
// tile S[rowset][r0+rl] for the same index partition. 8-lane DPP butterflies
// for all reductions. A = S S^T S via exact rank-3 recurrence; ||S||_F^2 via
// scalar recurrence. Math is bit-identical to the R3/R7 kernel.
__global__ SCAN_REGS __launch_bounds__(512)
void scan_kernel(
        const float* __restrict__ kphi, const float* __restrict__ qphi,
        const float* __restrict__ x, const float* __restrict__ M0,
        const float* __restrict__ S0, float* __restrict__ ys) {
    const int b    = blockIdx.x;
    const int tid  = threadIdx.x;
    const int j    = tid & 7;
    const int g    = tid >> 3;
    const int r0   = 2 * g;
    const int w    = tid >> 6;
    const int lane = tid & 63;

    __shared__ __align__(16) float kc[2][CH * DD];
    __shared__ __align__(16) float qc[2][CH * DD];
    __shared__ __align__(16) float xc[2][CH * DD];
    __shared__ __align__(16) float yc[CH * DD];
    __shared__ __align__(16) float us[DD], ps[DD], wsv[DD], hs[DD];
    __shared__ float red[64];
    __shared__ float n2sh;

    float S[32], ST[32], A[32], M[32];
    {
        const float4* S04 = (const float4*)S0;
        const float4* M04 = (const float4*)M0;
        #pragma unroll
        for (int rl = 0; rl < 2; ++rl)
            #pragma unroll
            for (int m = 0; m < 4; ++m) {
                int f4 = (r0 + rl) * 32 + j + 8 * m;
                float4 s4 = S04[f4], m4 = M04[f4];
                int i = rl * 16 + 4 * m;
                S[i+0] = s4.x; S[i+1] = s4.y; S[i+2] = s4.z; S[i+3] = s4.w;
                M[i+0] = m4.x; M[i+1] = m4.y; M[i+2] = m4.z; M[i+3] = m4.w;
            }
        #pragma unroll
        for (int rl = 0; rl < 2; ++rl)
            #pragma unroll
            for (int m = 0; m < 4; ++m)
                #pragma unroll
                for (int l = 0; l < 4; ++l)
                    ST[rl*16 + 4*m + l] =
                        S0[(size_t)(4*j + 32*m + l) * DD + r0 + rl];
        #pragma unroll
        for (int i = 0; i < 32; ++i) A[i] = 0.f;   // exact when S0 == 0
    }

    // ||S0||^2 block reduction
    float sp = 0.f;
    #pragma unroll
    for (int i = 0; i < 32; ++i) sp = fmaf(S[i], S[i], sp);
    sp = red8(sp);
    if (j == 0) red[g] = sp;

    const size_t base = (size_t)b * LL * DD;

    // preload chunk 0 (each wave copies 3 x 1KB segments)
    #pragma unroll
    for (int i = 0; i < 3; ++i) {
        int seg = w * 3 + i, arr = seg >> 3, sub = seg & 7;
        const float* sp0 = (arr == 0 ? kphi : (arr == 1 ? qphi : x))
                           + base + sub * 256 + lane * 4;
        float* dp = (arr == 0 ? kc[0] : (arr == 1 ? qc[0] : xc[0]))
                    + sub * 256 + lane * 4;
        *(float4*)dp = *(const float4*)sp0;
    }
    __syncthreads();
    if (tid < 64) {
        float s = red[tid];
        #pragma unroll
        for (int m = 1; m <= 32; m <<= 1) s += __shfl_xor(s, m);
        if (tid == 0) n2sh = s;
    }
    __syncthreads();
    float n2 = n2sh;

    const float a = 0.9f, a2v = 0.81f, a3v = 0.729f;

    #pragma unroll 1
    for (int tc = 0; tc < NCH; ++tc) {
        const int cb = tc & 1;
        const float* kcb = kc[cb];
        const float* qcb = qc[cb];
        const float* xcb = xc[cb];

        #pragma unroll 1
        for (int sl = 0; sl < CH; ++sl) {
            const int so = sl * DD;

            // issue next-chunk staging loads at chunk start (drained ~1x/chunk)
            float4 pre0, pre1, pre2;
            const bool doPre = (sl == 0) && (tc + 1 < NCH);
            if (doPre) {
                const size_t nbg = base + (size_t)(tc + 1) * CH * DD;
                {
                    int seg = w * 3 + 0, arr = seg >> 3, sub = seg & 7;
                    pre0 = *(const float4*)((arr == 0 ? kphi : (arr == 1 ? qphi : x))
                                            + nbg + sub * 256 + lane * 4);
                }
                {
                    int seg = w * 3 + 1, arr = seg >> 3, sub = seg & 7;
                    pre1 = *(const float4*)((arr == 0 ? kphi : (arr == 1 ? qphi : x))
                                            + nbg + sub * 256 + lane * 4);
                }
                {
                    int seg = w * 3 + 2, arr = seg >> 3, sub = seg & 7;
                    pre2 = *(const float4*)((arr == 0 ? kphi : (arr == 1 ? qphi : x))
                                            + nbg + sub * 256 + lane * 4);
                }
            }

            // ---- phase 2 (row side): pred = M k, p = S v, cv = v.v ----
            float kk[16];
            {
                const float4* k4 = (const float4*)(kcb + so);
                #pragma unroll
                for (int m = 0; m < 4; ++m) {
                    float4 v4 = k4[j + 8 * m];
                    kk[4*m+0] = v4.x; kk[4*m+1] = v4.y;
                    kk[4*m+2] = v4.z; kk[4*m+3] = v4.w;
                }
            }
            float pr0 = 0.f, pr1 = 0.f, pp0 = 0.f, pp1 = 0.f, cvp = 0.f;
            #pragma unroll
            for (int cl = 0; cl < 16; ++cl) {
                float kv = kk[cl];
                pr0 = fmaf(M[cl],      kv, pr0);
                pr1 = fmaf(M[16 + cl], kv, pr1);
                pp0 = fmaf(S[cl],      kv, pp0);
                pp1 = fmaf(S[16 + cl], kv, pp1);
                cvp = fmaf(kv, kv, cvp);
            }
            pr0 = red8(pr0); pr1 = red8(pr1);
            pp0 = red8(pp0); pp1 = red8(pp1);
            const float cv = red8(cvp);
            const float2 xv = *(const float2*)&xcb[so + r0];
            const float u0 = pr0 - xv.x, u1 = pr1 - xv.y;
            const float p0 = pp0, p1 = pp1;
            if (j == 0) {
                *(float2*)&us[r0] = make_float2(u0, u1);
                *(float2*)&ps[r0] = make_float2(p0, p1);
            }
            __syncthreads();                               // barrier 1 (LDS only)

            // ---- phase 4 (col side): w = S^T u, h = S^T p, dots; ST update ----
            float uu[16], pa[16];
            {
                const float4* u4 = (const float4*)us;
                const float4* p4 = (const float4*)ps;
                #pragma unroll
                for (int m = 0; m < 4; ++m) {
                    float4 a4 = u4[j + 8 * m], b4 = p4[j + 8 * m];
                    uu[4*m+0] = a4.x; uu[4*m+1] = a4.y;
                    uu[4*m+2] = a4.z; uu[4*m+3] = a4.w;
                    pa[4*m+0] = b4.x; pa[4*m+1] = b4.y;
                    pa[4*m+2] = b4.z; pa[4*m+3] = b4.w;
                }
            }
            const float2 vc = *(const float2*)&kcb[so + r0];
            float w0 = 0.f, w1 = 0.f, h0 = 0.f, h1 = 0.f, cuup = 0.f, cupp = 0.f;
            #pragma unroll
            for (int cl = 0; cl < 16; ++cl) {
                float uv = uu[cl], pv = pa[cl];
                float st0 = ST[cl], st1 = ST[16 + cl];
                w0 = fmaf(st0, uv, w0);  w1 = fmaf(st1, uv, w1);
                h0 = fmaf(st0, pv, h0);  h1 = fmaf(st1, pv, h1);
                cuup = fmaf(uv, uv, cuup);
                cupp = fmaf(uv, pv, cupp);
                ST[cl]      = fmaf(a, st0, vc.x * uv);     // old st used above only
                ST[16 + cl] = fmaf(a, st1, vc.y * uv);
            }
            w0 = red8(w0); w1 = red8(w1); h0 = red8(h0); h1 = red8(h1);
            const float cu  = red8(cuup);
            const float cup = red8(cupp);
            n2 = a2v * n2 + 2.0f * a * cup + cu * cv;      // ||S_t||_F^2 recurrence
            if (j == 0) {
                *(float2*)&wsv[r0] = make_float2(w0, w1);
                *(float2*)&hs[r0]  = make_float2(h0, h1);
            }
            // commit next-chunk staging to the other LDS buffer
            if (doPre) {
                float* kn = kc[cb ^ 1]; float* qn = qc[cb ^ 1]; float* xn = xc[cb ^ 1];
                {
                    int seg = w * 3 + 0, arr = seg >> 3, sub = seg & 7;
                    *(float4*)((arr == 0 ? kn : (arr == 1 ? qn : xn))
                               + sub * 256 + lane * 4) = pre0;
                }
                {
                    int seg = w * 3 + 1, arr = seg >> 3, sub = seg & 7;
                    *(float4*)((arr == 0 ? kn : (arr == 1 ? qn : xn))
                               + sub * 256 + lane * 4) = pre1;
                }
                {
                    int seg = w * 3 + 2, arr = seg >> 3, sub = seg & 7;
                    *(float4*)((arr == 0 ? kn : (arr == 1 ? qn : xn))
                               + sub * 256 + lane * 4) = pre2;
                }
            }
            __syncthreads();                               // barrier 2 (LDS only*)

            // ---- phase 6 (row side): g = S w; rank-3 A; S, M updates; y = M q ----
            float ww[16], hh[16], qq[16];
            {
                const float4* w4 = (const float4*)wsv;
                const float4* h4 = (const float4*)hs;
                const float4* q4 = (const float4*)(qcb + so);
                #pragma unroll
                for (int m = 0; m < 4; ++m) {
                    float4 a4 = w4[j + 8 * m], b4 = h4[j + 8 * m], c4v = q4[j + 8 * m];
                    ww[4*m+0] = a4.x;  ww[4*m+1] = a4.y;
                    ww[4*m+2] = a4.z;  ww[4*m+3] = a4.w;
                    hh[4*m+0] = b4.x;  hh[4*m+1] = b4.y;
                    hh[4*m+2] = b4.z;  hh[4*m+3] = b4.w;
                    qq[4*m+0] = c4v.x; qq[4*m+1] = c4v.y;
                    qq[4*m+2] = c4v.z; qq[4*m+3] = c4v.w;
                }
            }
            float g0 = 0.f, g1 = 0.f;
            #pragma unroll
            for (int cl = 0; cl < 16; ++cl) {
                g0 = fmaf(S[cl],      ww[cl], g0);
                g1 = fmaf(S[16 + cl], ww[cl], g1);
            }
            g0 = red8(g0); g1 = red8(g1);

            const float rho0 = a2v * g0 + a * cu * p0 + (a * cup + cv * cu) * u0;
            const float rho1 = a2v * g1 + a * cu * p1 + (a * cup + cv * cu) * u1;
            const float sg0  = a2v * p0 + a * cv * u0;
            const float sg1  = a2v * p1 + a * cv * u1;
            const float ta0  = a2v * u0, ta1 = a2v * u1;
            const float nrm  = sqrtf(fmaxf(n2, 0.f)) + 1e-6f;
            const float rn   = 1.0f / nrm;
            const float c1   = -0.015f * rn;    // 0.99M - 0.01*(1.5 S/n - 0.5 A/n^3)
            const float c2   = 0.005f * rn * rn * rn;

            float y0 = 0.f, y1 = 0.f;
            #pragma unroll
            for (int cl = 0; cl < 16; ++cl) {
                float kv = kk[cl], wv = ww[cl], hv = hh[cl], qv = qq[cl];
                S[cl]      = fmaf(a, S[cl],      u0 * kv);
                S[16 + cl] = fmaf(a, S[16 + cl], u1 * kv);
                A[cl]      = fmaf(a3v, A[cl],
                                  fmaf(rho0, kv, fmaf(sg0, wv, ta0 * hv)));
                A[16 + cl] = fmaf(a3v, A[16 + cl],
                                  fmaf(rho1, kv, fmaf(sg1, wv, ta1 * hv)));
                M[cl]      = fmaf(0.99f, M[cl],      fmaf(c1, S[cl],      c2 * A[cl]));
                M[16 + cl] = fmaf(0.99f, M[16 + cl], fmaf(c1, S[16 + cl], c2 * A[16 + cl]));
                y0 = fmaf(M[cl],      qv, y0);
                y1 = fmaf(M[16 + cl], qv, y1);
            }
            y0 = red8(y0); y1 = red8(y1);
            if (j == 0)
                *(float2*)&yc[so + r0] = make_float2(y0, y1);
        }

        // chunk end: flush yc -> ys (one float4 per thread)
        __syncthreads();
        float4 yv = *(float4*)&yc[tid * 4];
        *(float4*)(ys + base + (size_t)tc * CH * DD + tid * 4) = yv;
    }
}

// ---------------- epilogue: out = ys @ Wout^T + bout ---------------------------
__global__ __launch_bounds__(128) void epilogue_kernel(
        const float* __restrict__ ys, const float* __restrict__ WoutT,
        const float* __restrict__ bout, float* __restrict__ out) {
    const int row0 = blockIdx.x * 4;
    const int e = threadIdx.x;
    __shared__ float yr[4][DD];
    #pragma unroll
    for (int rr = 0; rr < 4; ++rr)
        yr[rr][e] = ys[(size_t)(row0 + rr) * DD + e];
    __syncthreads();
    float acc[4] = {0,0,0,0};
    #pragma unroll 4
    for (int d = 0; d < DD; ++d) {
        float w = WoutT[d * DD + e];
        #pragma unroll
        for (int rr = 0; rr < 4; ++rr) acc[rr] = fmaf(yr[rr][d], w, acc[rr]);
    }
    const float bo = bout[e];
    #pragma unroll
    for (int rr = 0; rr < 4; ++rr)
        out[(size_t)(row0 + rr) * DD + e] = acc[rr] + bo;
}

extern "C" void kernel_launch(void* const* d_in, const int* in_sizes, int n_in,
                              void* d_out, int out_size, void* d_ws, size_t ws_size,
                              hipStream_t stream) {
    const float* x        = (const float*)d_in[0];
    const float* Wq       = (const float*)d_in[1];
    const float* Wk       = (const float*)d_in[2];
    const float* P0       = (const float*)d_in[3];
    const float* M0       = (const float*)d_in[4];
    const float* S0       = (const float*)d_in[5];
    const float* log_gain = (const float*)d_in[6];
    const float* coeffs   = (const float*)d_in[7];
    const float* Wout     = (const float*)d_in[8];
    const float* bout     = (const float*)d_in[9];
    float* out = (float*)d_out;

    float* ws    = (float*)d_ws;
    float* WqT   = ws;                      // 16384
    float* WkT   = ws + 16384;              // 16384
    float* WoutT = ws + 32768;              // 16384
    float* kphi  = ws + 49152;              // B*L*D each below
    float* qphi  = kphi + (size_t)BB * LL * DD;
    float* ysb   = qphi + (size_t)BB * LL * DD;

    hipLaunchKernelGGL(transpose3_kernel, dim3(3), dim3(256), 0, stream,
                       Wq, Wk, Wout, WqT, WkT, WoutT);
    hipLaunchKernelGGL(prologue_kernel, dim3(BB * LL / 4), dim3(128), 0, stream,
                       x, WqT, WkT, P0, log_gain, coeffs, kphi, qphi);
    hipLaunchKernelGGL(scan_kernel, dim3(BB), dim3(512), 0, stream,
                       kphi, qphi, x, M0, S0, ysb);
    hipLaunchKernelGGL(epilogue_kernel, dim3(BB * LL / 4), dim3(128), 0, stream,
                       ysb, WoutT, bout, out);
}